// Round 6
// baseline (882.790 us; speedup 1.0000x reference)
//
#include <hip/hip_runtime.h>
#include <hip/hip_bf16.h>

// out[M,N] = X[M,K] @ W[K,N] + (X@A)@B + bias;  M=16384, N=K=4096.
// P1: X -> bf16.  P2: Wt[n][k] = bf16(W[k][n] + lora).
// G: 256x256 tile, 8 waves (2x4), 16x16x32 MFMA. A: LDS (swizzled, gload_lds dbuf).
//    B: DIRECT global->register (no LDS bounce). 2 phases/K-tile, 32 MFMA each.

typedef __attribute__((ext_vector_type(8))) __bf16 bf16x8;
typedef __attribute__((ext_vector_type(4))) float f32x4;

#define M_DIM 16384
#define N_DIM 4096
#define K_DIM 4096

__device__ __forceinline__ void async16(const void* g, void* l) {
    __builtin_amdgcn_global_load_lds((const __attribute__((address_space(1))) void*)g,
                                     (__attribute__((address_space(3))) void*)l,
                                     16, 0, 0);
}

// ---------------- P1: cast X to bf16 ----------------
__global__ void cast_x_kernel(const float* __restrict__ x, __bf16* __restrict__ xb, size_t n) {
    size_t i0 = ((size_t)blockIdx.x * blockDim.x + threadIdx.x) * 8;
    size_t stride = (size_t)gridDim.x * blockDim.x * 8;
    for (size_t i = i0; i < n; i += stride) {
        f32x4 v0 = __builtin_nontemporal_load((const f32x4*)(x + i));
        f32x4 v1 = __builtin_nontemporal_load((const f32x4*)(x + i + 4));
        bf16x8 o;
        o[0] = (__bf16)v0[0]; o[1] = (__bf16)v0[1]; o[2] = (__bf16)v0[2]; o[3] = (__bf16)v0[3];
        o[4] = (__bf16)v1[0]; o[5] = (__bf16)v1[1]; o[6] = (__bf16)v1[2]; o[7] = (__bf16)v1[3];
        *(bf16x8*)(xb + i) = o;
    }
}

// ---------------- P2: Wt[n][k] = bf16(W[k][n] + lora) ----------------
__global__ void prep_w_kernel(const float* __restrict__ W, const float* __restrict__ A,
                              const float* __restrict__ Bm, __bf16* __restrict__ Wt) {
    __shared__ float Ws[32][33];
    __shared__ float As[32][16];
    __shared__ float Bs[16][32];
    const int tx = threadIdx.x;
    const int ty = threadIdx.y;
    const int t = ty * 32 + tx;
    const int n0 = blockIdx.x * 32;
    const int k0 = blockIdx.y * 32;

#pragma unroll
    for (int i = 0; i < 4; ++i) {
        int k = ty + i * 8;
        Ws[k][tx] = W[(size_t)(k0 + k) * N_DIM + n0 + tx];
    }
    for (int i = t; i < 512; i += 256)
        As[i >> 4][i & 15] = A[(size_t)(k0 + (i >> 4)) * 16 + (i & 15)];
    for (int i = t; i < 512; i += 256)
        Bs[i >> 5][i & 31] = Bm[(size_t)(i >> 5) * N_DIM + n0 + (i & 31)];
    __syncthreads();

    float a[16];
#pragma unroll
    for (int r = 0; r < 16; ++r) a[r] = As[tx][r];
#pragma unroll
    for (int i = 0; i < 4; ++i) {
        int n = ty + i * 8;
        float acc = Ws[tx][n];
#pragma unroll
        for (int r = 0; r < 16; ++r) acc += a[r] * Bs[r][n];
        Wt[(size_t)(n0 + n) * K_DIM + k0 + tx] = (__bf16)acc;
    }
}

// ---------------- G: 256x256, A-in-LDS / B-in-regs, 2 phases per K-tile ----------------
// 512 threads = 8 waves (2 wr x 4 wn). Per wave 128x64 out = 8x4 frags of 16x16.
// LDS: 2 bufs x A[256][64] bf16 = 64 KiB, col-swizzle elem-group g -> g ^ (row&7).
// B: bfr[2][2][2] regs; loaded direct from Wt after last use (Ph1), consumed next tile.
// Per K-tile: Ph0 {ds af0 (8), stage A(t+1)HT0 (2), BAR, 32 MFMA MH0, vmcnt(2), BAR}
//             Ph1 {ds af1 (8), stage A(t+1)HT1 (2), BAR, 32 MFMA MH1, BLOAD(t+1) (8),
//                  vmcnt(10), BAR}
// FIFO ledger (per-phase issues: Ph0 [A2], Ph1 [A2, B8]):
//   enter Ph0(t): 10 = [A(t)HT1 x2, B(t) x8]  (compiler auto-waits B before MFMA)
//   end Ph0(t): 12 -> vmcnt(2) drains A(t)HT1 (+B(t), already needed) ; keep A(t+1)HT0
//   end Ph1(t): 12 -> vmcnt(10) drains A(t+1)HT0 ; keep [A(t+1)HT1, B(t+1)]

#define WAIT_VM(N) asm volatile("s_waitcnt vmcnt(" #N ")" ::: "memory")
#define BARRIER() do { asm volatile("" ::: "memory"); __builtin_amdgcn_s_barrier(); asm volatile("" ::: "memory"); } while (0)

#define STAGE_A(ldsbase, row0, kt) do {                                              \
    int r_ = (row0) + srow;                                                          \
    async16(Xb + (size_t)(m0 + r_) * K_DIM + (kt) + scol,                            \
            (ldsbase) + (row0) * 128 + sldsoff); } while (0)

#define LOAD_AF(ldsbase, MH)                                                         \
    _Pragma("unroll") for (int m_ = 0; m_ < 4; ++m_)                                 \
    _Pragma("unroll") for (int ks_ = 0; ks_ < 2; ++ks_)                              \
        afr[m_][ks_] = *(const bf16x8*)((ldsbase) + aRowB + (MH) * 8192 + m_ * 2048 + colsw[ks_]);

#define BLOAD(KT2)                                                                   \
    _Pragma("unroll") for (int nh_ = 0; nh_ < 2; ++nh_)                              \
    _Pragma("unroll") for (int nf_ = 0; nf_ < 2; ++nf_)                              \
    _Pragma("unroll") for (int ks_ = 0; ks_ < 2; ++ks_)                              \
        bfr[nh_][nf_][ks_] = *(const bf16x8*)(bbase[nh_][nf_] + (KT2) + ks_ * 32);

#define MFMA32(MH)                                                                   \
    __builtin_amdgcn_s_setprio(1);                                                   \
    _Pragma("unroll") for (int ks_ = 0; ks_ < 2; ++ks_)                              \
    _Pragma("unroll") for (int m_ = 0; m_ < 4; ++m_)                                 \
    _Pragma("unroll") for (int nh_ = 0; nh_ < 2; ++nh_)                              \
    _Pragma("unroll") for (int nf_ = 0; nf_ < 2; ++nf_)                              \
        acc[(MH) * 4 + m_][nh_ * 2 + nf_] = __builtin_amdgcn_mfma_f32_16x16x32_bf16( \
            afr[m_][ks_], bfr[nh_][nf_][ks_], acc[(MH) * 4 + m_][nh_ * 2 + nf_], 0, 0, 0); \
    __builtin_amdgcn_s_setprio(0);

#define PH0(AC, AO, KT)                                                              \
    LOAD_AF(AC, 0);                                                                  \
    STAGE_A(AO, 0, (KT) + 64); STAGE_A(AO, 128, (KT) + 64);                          \
    BARRIER(); MFMA32(0); WAIT_VM(2); BARRIER();

#define PH1(AC, AO, KT)                                                              \
    LOAD_AF(AC, 1);                                                                  \
    STAGE_A(AO, 64, (KT) + 64); STAGE_A(AO, 192, (KT) + 64);                         \
    BARRIER(); MFMA32(1); BLOAD((KT) + 64); WAIT_VM(10); BARRIER();

__global__ __launch_bounds__(512, 2) void gemm256_kernel(
    const __bf16* __restrict__ Xb, const __bf16* __restrict__ Wt,
    const float* __restrict__ bias, float* __restrict__ out) {
    extern __shared__ __align__(16) char smem[];
    const int tid  = threadIdx.x;
    const int lane = tid & 63;
    const int wave = tid >> 6;
    const int wr = wave >> 2;   // 0..1
    const int wn = wave & 3;    // 0..3

    const int bid = blockIdx.x;
    const int wg = (bid & 7) * 128 + (bid >> 3);   // XCD swizzle, 1024 % 8 == 0
    const int m0 = (wg >> 4) * 256;
    const int n0 = (wg & 15) * 256;

    char* A0 = smem;
    char* A1 = smem + 32768;

    // staging constants: thread covers row (row0 + srow), 16B group (tid&7)
    const int srow = tid >> 3;
    const int scol = ((tid & 7) ^ (srow & 7)) << 3;   // inverse-swizzled source col (elems)
    const int sldsoff = wave * 1024;                  // wave-uniform LDS offset in chunk

    // A frag-read constants (R4-verified conflict-free pattern)
    int colsw[2];
#pragma unroll
    for (int ks = 0; ks < 2; ++ks)
        colsw[ks] = ((ks * 32 + (lane >> 4) * 8) ^ ((lane & 7) * 8)) << 1;
    const int aRowB = (wr * 128 + (lane & 15)) * 128;

    // B direct-load bases: row = n0 + wn*64 + nh*32 + nf*16 + (lane&15), k-lo = (lane>>4)*8
    const __bf16* bbase[2][2];
#pragma unroll
    for (int nh = 0; nh < 2; ++nh)
#pragma unroll
        for (int nf = 0; nf < 2; ++nf)
            bbase[nh][nf] = Wt + (size_t)(n0 + wn * 64 + nh * 32 + nf * 16 + (lane & 15)) * K_DIM
                               + (lane >> 4) * 8;

    f32x4 acc[8][4] = {};
    bf16x8 afr[4][2], bfr[2][2][2];

    // ---- prologue: [A(0)HT0 x2] [B(0) x8] [A(0)HT1 x2]; vmcnt(10) drains HT0
    STAGE_A(A0, 0, 0);  STAGE_A(A0, 128, 0);
    BLOAD(0);
    STAGE_A(A0, 64, 0); STAGE_A(A0, 192, 0);
    WAIT_VM(10);
    BARRIER();

    // ---- main loop: tiles 0..61 (A-stages reference t+1 <= 62, B-loads t+1 <= 62)
    for (int it = 0; it < 31; ++it) {
        const int kt = it * 128;
        PH0(A0, A1, kt);       PH1(A0, A1, kt);
        PH0(A1, A0, kt + 64);  PH1(A1, A0, kt + 64);
    }

    // ---- tile 62 (A0, kt=3968): normal body; stages A(63), loads B(63)
    PH0(A0, A1, 3968);
    PH1(A0, A1, 3968);

    // ---- tile 63 (A1, kt=4032): tail — no stages, no B-loads
    LOAD_AF(A1, 0);
    BARRIER(); MFMA32(0); WAIT_VM(0); BARRIER();
    LOAD_AF(A1, 1);
    BARRIER(); MFMA32(1);

    // ---- epilogue: C/D map col=lane&15, row=(lane>>4)*4+j; nontemporal out stream
#pragma unroll
    for (int mh = 0; mh < 2; ++mh)
#pragma unroll
        for (int m = 0; m < 4; ++m) {
            const int gr = m0 + wr * 128 + mh * 64 + m * 16 + (lane >> 4) * 4;
#pragma unroll
            for (int nh = 0; nh < 2; ++nh)
#pragma unroll
                for (int n = 0; n < 2; ++n) {
                    const int gc = n0 + wn * 64 + nh * 32 + n * 16 + (lane & 15);
                    const float bv = bias[gc];
                    const f32x4 a = acc[mh * 4 + m][nh * 2 + n];
#pragma unroll
                    for (int j = 0; j < 4; ++j)
                        __builtin_nontemporal_store(a[j] + bv,
                            &out[(size_t)(gr + j) * N_DIM + gc]);
                }
        }
}

extern "C" void kernel_launch(void* const* d_in, const int* in_sizes, int n_in,
                              void* d_out, int out_size, void* d_ws, size_t ws_size,
                              hipStream_t stream) {
    const float* x    = (const float*)d_in[0];
    const float* W    = (const float*)d_in[1];
    const float* bias = (const float*)d_in[2];
    const float* lA   = (const float*)d_in[3];
    const float* lB   = (const float*)d_in[4];
    float* out = (float*)d_out;

    __bf16* Xb = (__bf16*)d_ws;
    __bf16* Wt = (__bf16*)((char*)d_ws + (size_t)M_DIM * K_DIM * 2);

    cast_x_kernel<<<2048, 256, 0, stream>>>(x, Xb, (size_t)M_DIM * K_DIM);
    prep_w_kernel<<<dim3(N_DIM / 32, K_DIM / 32), dim3(32, 8), 0, stream>>>(W, lA, lB, Wt);

    (void)hipFuncSetAttribute((const void*)gemm256_kernel,
                              hipFuncAttributeMaxDynamicSharedMemorySize, 65536);
    gemm256_kernel<<<1024, 512, 65536, stream>>>(Xb, Wt, bias, out);
}

// Round 7
// 587.622 us; speedup vs baseline: 1.5023x; 1.5023x over previous
//
#include <hip/hip_runtime.h>
#include <hip/hip_bf16.h>

// out[M,N] = X[M,K] @ W[K,N] + (X@A)@B + bias;  M=16384, N=K=4096.
// P1: X -> bf16.  P2: Wt[n][k] = bf16(W[k][n] + lora).
// G: 256x256 tile, 8 waves (2x4), 16x16x32 MFMA, 2 phases per K-tile(64).

typedef __attribute__((ext_vector_type(8))) __bf16 bf16x8;
typedef __attribute__((ext_vector_type(4))) float f32x4;

#define M_DIM 16384
#define N_DIM 4096
#define K_DIM 4096

__device__ __forceinline__ void async16(const void* g, void* l) {
    __builtin_amdgcn_global_load_lds((const __attribute__((address_space(1))) void*)g,
                                     (__attribute__((address_space(3))) void*)l,
                                     16, 0, 0);
}

// ---------------- P1: cast X to bf16 ----------------
__global__ void cast_x_kernel(const float* __restrict__ x, __bf16* __restrict__ xb, size_t n) {
    size_t i0 = ((size_t)blockIdx.x * blockDim.x + threadIdx.x) * 8;
    size_t stride = (size_t)gridDim.x * blockDim.x * 8;
    for (size_t i = i0; i < n; i += stride) {
        f32x4 v0 = __builtin_nontemporal_load((const f32x4*)(x + i));
        f32x4 v1 = __builtin_nontemporal_load((const f32x4*)(x + i + 4));
        bf16x8 o;
        o[0] = (__bf16)v0[0]; o[1] = (__bf16)v0[1]; o[2] = (__bf16)v0[2]; o[3] = (__bf16)v0[3];
        o[4] = (__bf16)v1[0]; o[5] = (__bf16)v1[1]; o[6] = (__bf16)v1[2]; o[7] = (__bf16)v1[3];
        *(bf16x8*)(xb + i) = o;
    }
}

// ---------------- P2: Wt[n][k] = bf16(W[k][n] + lora) ----------------
__global__ void prep_w_kernel(const float* __restrict__ W, const float* __restrict__ A,
                              const float* __restrict__ Bm, __bf16* __restrict__ Wt) {
    __shared__ float Ws[32][33];
    __shared__ float As[32][16];
    __shared__ float Bs[16][32];
    const int tx = threadIdx.x;
    const int ty = threadIdx.y;
    const int t = ty * 32 + tx;
    const int n0 = blockIdx.x * 32;
    const int k0 = blockIdx.y * 32;

#pragma unroll
    for (int i = 0; i < 4; ++i) {
        int k = ty + i * 8;
        Ws[k][tx] = W[(size_t)(k0 + k) * N_DIM + n0 + tx];
    }
    for (int i = t; i < 512; i += 256)
        As[i >> 4][i & 15] = A[(size_t)(k0 + (i >> 4)) * 16 + (i & 15)];
    for (int i = t; i < 512; i += 256)
        Bs[i >> 5][i & 31] = Bm[(size_t)(i >> 5) * N_DIM + n0 + (i & 31)];
    __syncthreads();

    float a[16];
#pragma unroll
    for (int r = 0; r < 16; ++r) a[r] = As[tx][r];
#pragma unroll
    for (int i = 0; i < 4; ++i) {
        int n = ty + i * 8;
        float acc = Ws[tx][n];
#pragma unroll
        for (int r = 0; r < 16; ++r) acc += a[r] * Bs[r][n];
        Wt[(size_t)(n0 + n) * K_DIM + k0 + tx] = (__bf16)acc;
    }
}

// ---------------- G: 256x256, 2 phases per K-tile(64), 16x16x32 MFMA ----------------
// 512 threads = 8 waves (2 wr x 4 wn). Per wave 128x64 out = 8x4 frags of 16x16.
// LDS: A0,A1,B0,B1 x 32 KiB = 128 KiB; col-swizzle elem-group g -> g ^ (row&7).
// B rows stored nh-permuted: phys p = nh*128 + wn*32 + s <-> logical n = wn*64+nh*32+s.
// Ph0(t): ds{A-MH0 8, B both 8}, stage A(t+1)->alt (4), BAR, 32 MFMA (MH0), BAR.
// Ph1(t): ds{A-MH1 8}, stage B(t+2)->CURRENT B-buf (4; B(t) fully read in Ph0),
//         BAR, 32 MFMA (MH1), vmcnt(4), BAR.
// FIFO ledger (4 loads/slot): enter Ph0(t) with [B(t+1)x4] in flight, A(t)/B(t) landed.
//   Ph0 issues A(t+1) -> 8; Ph1 issues B(t+2) -> 12; vmcnt(4) drains B(t+1),A(t+1). OK.

#define WAIT_VM(N) asm volatile("s_waitcnt vmcnt(" #N ")" ::: "memory")
#define BARRIER() do { asm volatile("" ::: "memory"); __builtin_amdgcn_s_barrier(); asm volatile("" ::: "memory"); } while (0)

#define STAGE_A(ldsbase, row0, kt) do {                                              \
    int r_ = (row0) + srow;                                                          \
    async16(Xb + (size_t)(m0 + r_) * K_DIM + (kt) + scol,                            \
            (ldsbase) + (row0) * 128 + sldsoff); } while (0)

#define STAGE_B(ldsbase, row0, kt) do {                                              \
    int p_ = (row0) + srow;                                                          \
    int nl_ = ((p_ >> 5) & 3) * 64 + ((p_ >> 7) & 1) * 32 + (p_ & 31);               \
    async16(Wt + (size_t)(n0 + nl_) * K_DIM + (kt) + scol,                           \
            (ldsbase) + (row0) * 128 + sldsoff); } while (0)

#define LOAD_AF(ldsbase, MH)                                                         \
    _Pragma("unroll") for (int m_ = 0; m_ < 4; ++m_)                                 \
    _Pragma("unroll") for (int ks_ = 0; ks_ < 2; ++ks_)                              \
        afr[m_][ks_] = *(const bf16x8*)((ldsbase) + aRowB + (MH) * 8192 + m_ * 2048 + colsw[ks_]);

#define LOAD_BF(dst, ldsbase, NH)                                                    \
    _Pragma("unroll") for (int n_ = 0; n_ < 2; ++n_)                                 \
    _Pragma("unroll") for (int ks_ = 0; ks_ < 2; ++ks_)                              \
        dst[n_][ks_] = *(const bf16x8*)((ldsbase) + bRowB + (NH) * 16384 + n_ * 2048 + colsw[ks_]);

#define MFMA32(MH)                                                                   \
    __builtin_amdgcn_s_setprio(1);                                                   \
    _Pragma("unroll") for (int ks_ = 0; ks_ < 2; ++ks_)                              \
    _Pragma("unroll") for (int m_ = 0; m_ < 4; ++m_) {                               \
        _Pragma("unroll") for (int n_ = 0; n_ < 2; ++n_)                             \
            acc[(MH) * 4 + m_][n_] = __builtin_amdgcn_mfma_f32_16x16x32_bf16(        \
                afr[m_][ks_], b0f[n_][ks_], acc[(MH) * 4 + m_][n_], 0, 0, 0);        \
        _Pragma("unroll") for (int n_ = 0; n_ < 2; ++n_)                             \
            acc[(MH) * 4 + m_][2 + n_] = __builtin_amdgcn_mfma_f32_16x16x32_bf16(    \
                afr[m_][ks_], b1f[n_][ks_], acc[(MH) * 4 + m_][2 + n_], 0, 0, 0);    \
    }                                                                                \
    __builtin_amdgcn_s_setprio(0);                                                   \
    __builtin_amdgcn_sched_barrier(0);

#define PH0(AC, BC, AO, KT)                                                          \
    LOAD_AF(AC, 0);                                                                  \
    LOAD_BF(b0f, BC, 0); LOAD_BF(b1f, BC, 1);                                        \
    STAGE_A(AO, 0, (KT) + 64);  STAGE_A(AO, 128, (KT) + 64);                         \
    STAGE_A(AO, 64, (KT) + 64); STAGE_A(AO, 192, (KT) + 64);                         \
    BARRIER(); MFMA32(0); BARRIER();

#define PH1(AC, BC, KT)                                                              \
    LOAD_AF(AC, 1);                                                                  \
    STAGE_B(BC, 0, (KT) + 128);   STAGE_B(BC, 64, (KT) + 128);                       \
    STAGE_B(BC, 128, (KT) + 128); STAGE_B(BC, 192, (KT) + 128);                      \
    BARRIER(); MFMA32(1); WAIT_VM(4); BARRIER();

__global__ __launch_bounds__(512, 2) void gemm256_kernel(
    const __bf16* __restrict__ Xb, const __bf16* __restrict__ Wt,
    const float* __restrict__ bias, float* __restrict__ out) {
    extern __shared__ __align__(16) char smem[];
    const int tid  = threadIdx.x;
    const int lane = tid & 63;
    const int wave = tid >> 6;
    const int wr = wave >> 2;   // 0..1
    const int wn = wave & 3;    // 0..3

    const int bid = blockIdx.x;
    const int wg = (bid & 7) * 128 + (bid >> 3);   // XCD swizzle, 1024 % 8 == 0
    const int m0 = (wg >> 4) * 256;
    const int n0 = (wg & 15) * 256;

    char* A0 = smem;
    char* B0 = smem + 32768;
    char* A1 = smem + 65536;
    char* B1 = smem + 98304;

    // staging constants: thread covers row (row0 + srow), 16B group (tid&7)
    const int srow = tid >> 3;
    const int scol = ((tid & 7) ^ (srow & 7)) << 3;   // inverse-swizzled source col (elems)
    const int sldsoff = wave * 1024;                  // wave-uniform LDS offset in chunk

    // frag-read constants (R4-verified conflict-free pattern)
    int colsw[2];
#pragma unroll
    for (int ks = 0; ks < 2; ++ks)
        colsw[ks] = ((ks * 32 + (lane >> 4) * 8) ^ ((lane & 7) * 8)) << 1;
    const int aRowB = (wr * 128 + (lane & 15)) * 128;
    const int bRowB = (wn * 32 + (lane & 15)) * 128;

    f32x4 acc[8][4] = {};
    bf16x8 afr[4][2], b0f[2][2], b1f[2][2];

    // ---- prologue: B(0)x4, A(0)x4, B(1)x4; vmcnt(4) leaves [B(1)x4] in flight
    STAGE_B(B0, 0, 0);   STAGE_B(B0, 64, 0);  STAGE_B(B0, 128, 0); STAGE_B(B0, 192, 0);
    STAGE_A(A0, 0, 0);   STAGE_A(A0, 128, 0); STAGE_A(A0, 64, 0);  STAGE_A(A0, 192, 0);
    STAGE_B(B1, 0, 64);  STAGE_B(B1, 64, 64); STAGE_B(B1, 128, 64); STAGE_B(B1, 192, 64);
    WAIT_VM(4);
    BARRIER();

    // ---- main loop: tiles 0..61 (A-stage refs t+1 <= 62, B-stage refs t+2 <= 63)
    for (int it = 0; it < 31; ++it) {
        const int kt = it * 128;
        PH0(A0, B0, A1, kt);       PH1(A0, B0, kt);
        PH0(A1, B1, A0, kt + 64);  PH1(A1, B1, kt + 64);
    }

    // ---- tile 62 (A0/B0, kt=3968): Ph0 stages A(63); Ph1 no stage, drain to 0
    PH0(A0, B0, A1, 3968);
    LOAD_AF(A0, 1);
    BARRIER(); MFMA32(1); WAIT_VM(0); BARRIER();

    // ---- tile 63 (A1/B1, kt=4032): no stages, no waits
    LOAD_AF(A1, 0);
    LOAD_BF(b0f, B1, 0); LOAD_BF(b1f, B1, 1);
    BARRIER(); MFMA32(0); BARRIER();
    LOAD_AF(A1, 1);
    MFMA32(1);

    // ---- epilogue: C/D map col=lane&15, row=(lane>>4)*4+j; nontemporal out stream
#pragma unroll
    for (int mh = 0; mh < 2; ++mh)
#pragma unroll
        for (int m = 0; m < 4; ++m) {
            const int gr = m0 + wr * 128 + mh * 64 + m * 16 + (lane >> 4) * 4;
#pragma unroll
            for (int nh = 0; nh < 2; ++nh)
#pragma unroll
                for (int n = 0; n < 2; ++n) {
                    const int gc = n0 + wn * 64 + nh * 32 + n * 16 + (lane & 15);
                    const float bv = bias[gc];
                    const f32x4 a = acc[mh * 4 + m][nh * 2 + n];
#pragma unroll
                    for (int j = 0; j < 4; ++j)
                        __builtin_nontemporal_store(a[j] + bv,
                            &out[(size_t)(gr + j) * N_DIM + gc]);
                }
        }
}

extern "C" void kernel_launch(void* const* d_in, const int* in_sizes, int n_in,
                              void* d_out, int out_size, void* d_ws, size_t ws_size,
                              hipStream_t stream) {
    const float* x    = (const float*)d_in[0];
    const float* W    = (const float*)d_in[1];
    const float* bias = (const float*)d_in[2];
    const float* lA   = (const float*)d_in[3];
    const float* lB   = (const float*)d_in[4];
    float* out = (float*)d_out;

    __bf16* Xb = (__bf16*)d_ws;
    __bf16* Wt = (__bf16*)((char*)d_ws + (size_t)M_DIM * K_DIM * 2);

    cast_x_kernel<<<2048, 256, 0, stream>>>(x, Xb, (size_t)M_DIM * K_DIM);
    prep_w_kernel<<<dim3(N_DIM / 32, K_DIM / 32), dim3(32, 8), 0, stream>>>(W, lA, lB, Wt);

    (void)hipFuncSetAttribute((const void*)gemm256_kernel,
                              hipFuncAttributeMaxDynamicSharedMemorySize, 131072);
    gemm256_kernel<<<1024, 512, 131072, stream>>>(Xb, Wt, bias, out);
}